// Round 5
// baseline (189.334 us; speedup 1.0000x reference)
//
#include <hip/hip_runtime.h>
#include <hip/hip_bf16.h>
#include <stdint.h>

// Problem constants
#define NB    32    // batch
#define CIN   128
#define HH    56
#define WW    56
#define COUT  256
#define HP    58    // padded height (H+2)
#define WP    64    // padded width (56+2 -> padded to 64)

// ws layout: xp (bf16, NB*HP*WP*CIN) then wpack (bf16, 9*4*4*256*8)
#define XP_ELEMS   (NB * HP * WP * CIN)

typedef __attribute__((ext_vector_type(4))) float f32x4;
typedef __attribute__((ext_vector_type(8))) short bf16x8;

__device__ __forceinline__ unsigned short f2bf(float f) {
    union { float f; unsigned u; } v; v.f = f;
    unsigned r = v.u + 0x7FFFu + ((v.u >> 16) & 1u);
    return (unsigned short)(r >> 16);
}

__device__ __forceinline__ void gload16(const void* g, void* l) {
    __builtin_amdgcn_global_load_lds(
        (__attribute__((address_space(1))) void*)(void*)g,
        (__attribute__((address_space(3))) void*)l,
        16, 0, 0);
}

// ---------------------------------------------------------------------------
// Pass A: compose per-output-channel filters, store bf16 in wpack layout
// wpack[pos(9)][cib(4)][kpos(4)][o(256)][kin(8)], ci = cib*32 + kpos*8 + kin
// ---------------------------------------------------------------------------
__global__ __launch_bounds__(256) void build_weight(
    const float* __restrict__ dict, const float* __restrict__ coef,
    const int* __restrict__ idxw, unsigned short* __restrict__ wpack) {
    int o = blockIdx.x;
    int tid = threadIdx.x;

    // Reference dtype is int64; detect int64 vs int32 storage.
    bool mode64 = (idxw[1] == 0) && (idxw[3] == 0) && (idxw[5] == 0) &&
                  (idxw[7] == 0) && (idxw[9] == 0) && (idxw[11] == 0) &&
                  (idxw[13] == 0) && (idxw[15] == 0);

    float c[8]; int di[8];
#pragma unroll
    for (int s = 0; s < 8; ++s) {
        c[s]  = coef[o * 8 + s];
        di[s] = mode64 ? idxw[(o * 8 + s) * 2] : idxw[o * 8 + s];
    }

    for (int j = tid; j < 9 * 128; j += 256) {
        int pos = j >> 7;          // 0..8
        int ci  = j & 127;
        int kh = pos / 3, kw = pos - kh * 3;
        float v = 0.f;
#pragma unroll
        for (int s = 0; s < 8; ++s)
            v += c[s] * dict[((di[s] * CIN + ci) * 3 + kh) * 3 + kw];
        int cib = ci >> 5, kpos = (ci >> 3) & 3, kin = ci & 7;
        wpack[((((pos * 4 + cib) * 4 + kpos) * COUT + o) << 3) + kin] = f2bf(v);
    }
}

// ---------------------------------------------------------------------------
// Pass B: NCHW fp32 -> zero-padded NHWC bf16, vectorized short8 stores
// xp[b][ih(58)][iw(64)][ci(128)]; valid x at ih in [1,56], iw in [1,56]
// ---------------------------------------------------------------------------
__global__ __launch_bounds__(256) void pack_x(
    const float* __restrict__ x, unsigned short* __restrict__ xp) {
    int ih = blockIdx.x;   // 0..57
    int b  = blockIdx.y;
    int tid = threadIdx.x;
    size_t obase = ((size_t)(b * HP + ih)) * WP * CIN;
    bf16x8* outv = (bf16x8*)(xp + obase);   // 1024 vectors of 8 bf16

    if (ih == 0 || ih == HP - 1) {
        bf16x8 z = {0, 0, 0, 0, 0, 0, 0, 0};
        for (int e = tid; e < WP * CIN / 8; e += 256) outv[e] = z;
        return;
    }

    __shared__ float xs[CIN][WW + 1];   // +1 pad: odd stride
    int h = ih - 1;
    for (int e = tid; e < CIN * WW; e += 256) {
        int ci = e / WW, w = e - ci * WW;
        xs[ci][w] = x[(((size_t)b * CIN + ci) * HH + h) * WW + w];
    }
    __syncthreads();
    for (int ch = tid; ch < WP * CIN / 8; ch += 256) {
        int iw = ch >> 4;            // 0..63
        int cb = (ch & 15) << 3;     // ci base, 0..120
        bf16x8 v = {0, 0, 0, 0, 0, 0, 0, 0};
        if (iw >= 1 && iw <= WW) {
#pragma unroll
            for (int j = 0; j < 8; ++j)
                v[j] = (short)f2bf(xs[cb + j][iw - 1]);
        }
        outv[ch] = v;
    }
}

// ---------------------------------------------------------------------------
// Main: implicit-GEMM conv.  Block = 256 Cout x 2 output rows (one b).
// 512 threads = 8 waves; wave tile 32(M) x 128(N): wave wid owns Cout rows
// [wid*32, wid*32+32), both output rows, all 64 iw cols (8 junk).
//
// A (weights) is NOT staged in LDS: wpack layout == fragment layout, so each
// lane global_load_dwordx4's its A-fragments straight into registers from
// the L2-resident 576 KB wpack, software-pipelined one tile ahead (afn).
// No two waves read the same A-fragment (8-way M split) -> A L2 traffic
// 32 KB/CU/iter.  B (x) stays in LDS, double-buffered, restaged once per
// cib -> only 4 __syncthreads per block; the 9 inner iterations run
// barrier-free so the 16 resident waves drift and hide L2 latency.
//
// LDS = 2 x 16 KB = 32 KB -> 2 blocks/CU (round-4 lesson: 80 KB forced
// 1 block/CU).  __launch_bounds__(512,4) caps regs at 128 to guarantee it;
// body ~111 regs (acc 64 + af 8 + afn 8 + br 16 + addr).
// ---------------------------------------------------------------------------
__global__ __launch_bounds__(512, 4) void conv_mfma(
    const unsigned short* __restrict__ xp,
    const unsigned short* __restrict__ wpack,
    float* __restrict__ out) {
    // B tile: [rr(4)][kpos(4)][iw(64)][kin(8)] = 8192 elems (16 KB), 2-deep
    __shared__ unsigned short Bl[2][4 * 4 * 64 * 8];

    int tid  = threadIdx.x;
    int lane = tid & 63;
    int wid  = tid >> 6;       // 0..7 = M slice
    int band = blockIdx.x;     // 0..27
    int b    = blockIdx.y;     // 0..31
    int oh0  = band * 2;

    const int klane = lane >> 4;   // k-group of this lane (0..3)
    const int fl    = lane & 15;

    // acc[mf][r][c]: mf = Cout 16-row frag (2), r = output row (2), c = iw chunk (4)
    f32x4 acc[2][2][4];
    f32x4 zero = {0.f, 0.f, 0.f, 0.f};
#pragma unroll
    for (int i = 0; i < 2; ++i)
#pragma unroll
        for (int j = 0; j < 2; ++j)
#pragma unroll
            for (int k = 0; k < 4; ++k) acc[i][j][k] = zero;

    // Per-lane A-fragment base: o = wid*32 + mf*16 + fl, frag elems at
    // tile*8192 + (klane*256 + o)*8  (bf16 elems)
    const unsigned short* ap = wpack + ((size_t)klane * 256 + wid * 32 + fl) * 8;

    // ---- prologue: stage B(cib=0); preload A(t=0) ----
#pragma unroll
    for (int tt = 0; tt < 2; ++tt) {
        int s = wid + tt * 8;
        int rr = s >> 2, kpos = s & 3;
        gload16(xp + (((size_t)(b * HP + oh0 + rr)) * WP + lane) * CIN + kpos * 8,
                &Bl[0][s * 512]);
    }
    bf16x8 afc[2], afn[2];
#pragma unroll
    for (int mf = 0; mf < 2; ++mf)
        afc[mf] = *(const bf16x8*)(ap + mf * 128);   // tile 0 = (pos0,cib0)
    __syncthreads();   // B(0) resident

#pragma unroll
    for (int t = 0; t < 36; ++t) {
        const int cib = t / 9, pos = t % 9;
        const int kh = pos / 3, kw = pos - kh * 3;
        const int bbuf = cib & 1;

        // ---- stage B(cib+1) once per cib, 9 barrier-free iters of slack ----
        if (pos == 0 && cib < 3) {
#pragma unroll
            for (int tt = 0; tt < 2; ++tt) {
                int s = wid + tt * 8;
                int rr = s >> 2, kpos = s & 3;
                gload16(xp + (((size_t)(b * HP + oh0 + rr)) * WP + lane) * CIN +
                            (cib + 1) * 32 + kpos * 8,
                        &Bl[bbuf ^ 1][s * 512]);
            }
        }

        // ---- prefetch A(t+1) fragments into registers ----
        if (t < 35) {
            const int t1 = t + 1;
            const int tile1 = (t1 % 9) * 4 + (t1 / 9);
#pragma unroll
            for (int mf = 0; mf < 2; ++mf)
                afn[mf] = *(const bf16x8*)(ap + (size_t)tile1 * 8192 + mf * 128);
        }

        // ---- B fragments from LDS + MFMA, one output row at a time ----
#pragma unroll
        for (int r = 0; r < 2; ++r) {
            const int rr = r + kh;
            bf16x8 br[4];
#pragma unroll
            for (int c = 0; c < 4; ++c) {
                int iw = c * 16 + fl + kw;
                if (c == 3) iw = iw > 63 ? 63 : iw;   // junk lanes -> zero cols
                br[c] = *(const bf16x8*)&Bl[bbuf][((rr * 4 + klane) * 64 + iw) * 8];
            }
#pragma unroll
            for (int mf = 0; mf < 2; ++mf)
#pragma unroll
                for (int c = 0; c < 4; ++c)
                    acc[mf][r][c] = __builtin_amdgcn_mfma_f32_16x16x32_bf16(
                        afc[mf], br[c], acc[mf][r][c], 0, 0, 0);
        }
        afc[0] = afn[0]; afc[1] = afn[1];

        // ---- single barrier per cib (end): B reads done + next B staged ----
        if (pos == 8 && t != 35) __syncthreads();
    }

    // Epilogue: C/D layout col = lane&15 -> ow, row = (lane>>4)*4 + reg -> ob
#pragma unroll
    for (int r = 0; r < 2; ++r) {
        int oh = oh0 + r;
#pragma unroll
        for (int c = 0; c < 4; ++c) {
            int ow = c * 16 + fl;
            if (ow < WW) {
#pragma unroll
                for (int mf = 0; mf < 2; ++mf) {
                    int ob = wid * 32 + mf * 16 + (lane >> 4) * 4;
                    float* dst = out + (((size_t)b * COUT + ob) * HH + oh) * WW + ow;
#pragma unroll
                    for (int reg = 0; reg < 4; ++reg)
                        dst[(size_t)reg * HH * WW] = acc[mf][r][c][reg];
                }
            }
        }
    }
}

extern "C" void kernel_launch(void* const* d_in, const int* in_sizes, int n_in,
                              void* d_out, int out_size, void* d_ws, size_t ws_size,
                              hipStream_t stream) {
    const float* x    = (const float*)d_in[0];
    const float* dict = (const float*)d_in[1];
    const float* coef = (const float*)d_in[2];
    const int*   idxw = (const int*)d_in[3];
    float* out = (float*)d_out;

    unsigned short* xp    = (unsigned short*)d_ws;
    unsigned short* wpack = xp + XP_ELEMS;

    build_weight<<<dim3(COUT), dim3(256), 0, stream>>>(dict, coef, idxw, wpack);
    pack_x<<<dim3(HP, NB), dim3(256), 0, stream>>>(x, xp);
    conv_mfma<<<dim3(HH / 2, NB), dim3(512), 0, stream>>>(xp, wpack, out);
}

// Round 6
// 104.085 us; speedup vs baseline: 1.8190x; 1.8190x over previous
//
#include <hip/hip_runtime.h>
#include <hip/hip_bf16.h>
#include <stdint.h>

// Problem constants
#define NB    32    // batch
#define CIN   128
#define HH    56
#define WW    56
#define COUT  256
#define HP    58    // padded height (H+2)
#define WP    64    // padded width (56+2 -> padded to 64)

// ws layout: xp (bf16, NB*HP*WP*CIN) then wpack (bf16, 9*4*4*256*8)
#define XP_ELEMS   (NB * HP * WP * CIN)

typedef __attribute__((ext_vector_type(4))) float f32x4;
typedef __attribute__((ext_vector_type(8))) short bf16x8;

__device__ __forceinline__ unsigned short f2bf(float f) {
    union { float f; unsigned u; } v; v.f = f;
    unsigned r = v.u + 0x7FFFu + ((v.u >> 16) & 1u);
    return (unsigned short)(r >> 16);
}

__device__ __forceinline__ void gload16(const void* g, void* l) {
    __builtin_amdgcn_global_load_lds(
        (__attribute__((address_space(1))) void*)(void*)g,
        (__attribute__((address_space(3))) void*)l,
        16, 0, 0);
}

// ---------------------------------------------------------------------------
// Pass A: compose per-output-channel filters, store bf16 in wpack layout
// wpack[pos(9)][cib(4)][kpos(4)][o(256)][kin(8)], ci = cib*32 + kpos*8 + kin
// ---------------------------------------------------------------------------
__global__ __launch_bounds__(256) void build_weight(
    const float* __restrict__ dict, const float* __restrict__ coef,
    const int* __restrict__ idxw, unsigned short* __restrict__ wpack) {
    int o = blockIdx.x;
    int tid = threadIdx.x;

    // Reference dtype is int64; detect int64 vs int32 storage.
    bool mode64 = (idxw[1] == 0) && (idxw[3] == 0) && (idxw[5] == 0) &&
                  (idxw[7] == 0) && (idxw[9] == 0) && (idxw[11] == 0) &&
                  (idxw[13] == 0) && (idxw[15] == 0);

    float c[8]; int di[8];
#pragma unroll
    for (int s = 0; s < 8; ++s) {
        c[s]  = coef[o * 8 + s];
        di[s] = mode64 ? idxw[(o * 8 + s) * 2] : idxw[o * 8 + s];
    }

    for (int j = tid; j < 9 * 128; j += 256) {
        int pos = j >> 7;          // 0..8
        int ci  = j & 127;
        int kh = pos / 3, kw = pos - kh * 3;
        float v = 0.f;
#pragma unroll
        for (int s = 0; s < 8; ++s)
            v += c[s] * dict[((di[s] * CIN + ci) * 3 + kh) * 3 + kw];
        int cib = ci >> 5, kpos = (ci >> 3) & 3, kin = ci & 7;
        wpack[((((pos * 4 + cib) * 4 + kpos) * COUT + o) << 3) + kin] = f2bf(v);
    }
}

// ---------------------------------------------------------------------------
// Pass B: NCHW fp32 -> zero-padded NHWC bf16, vectorized short8 stores
// xp[b][ih(58)][iw(64)][ci(128)]; valid x at ih in [1,56], iw in [1,56]
// ---------------------------------------------------------------------------
__global__ __launch_bounds__(256) void pack_x(
    const float* __restrict__ x, unsigned short* __restrict__ xp) {
    int ih = blockIdx.x;   // 0..57
    int b  = blockIdx.y;
    int tid = threadIdx.x;
    size_t obase = ((size_t)(b * HP + ih)) * WP * CIN;
    bf16x8* outv = (bf16x8*)(xp + obase);   // 1024 vectors of 8 bf16

    if (ih == 0 || ih == HP - 1) {
        bf16x8 z = {0, 0, 0, 0, 0, 0, 0, 0};
        for (int e = tid; e < WP * CIN / 8; e += 256) outv[e] = z;
        return;
    }

    __shared__ float xs[CIN][WW + 1];   // +1 pad: odd stride
    int h = ih - 1;
    for (int e = tid; e < CIN * WW; e += 256) {
        int ci = e / WW, w = e - ci * WW;
        xs[ci][w] = x[(((size_t)b * CIN + ci) * HH + h) * WW + w];
    }
    __syncthreads();
    for (int ch = tid; ch < WP * CIN / 8; ch += 256) {
        int iw = ch >> 4;            // 0..63
        int cb = (ch & 15) << 3;     // ci base, 0..120
        bf16x8 v = {0, 0, 0, 0, 0, 0, 0, 0};
        if (iw >= 1 && iw <= WW) {
#pragma unroll
            for (int j = 0; j < 8; ++j)
                v[j] = (short)f2bf(xs[cb + j][iw - 1]);
        }
        outv[ch] = v;
    }
}

// ---------------------------------------------------------------------------
// Main: implicit-GEMM conv.  Block = 256 Cout x 2 output rows (one b).
// 512 threads = 8 waves; wave grid 4(M) x 2(N); wave tile 64x64.
//
// Pipeline (T4, LDS-legal this time): A tiles 3-deep (prefetch distance 2),
// B SINGLE-buffered (changes only every 9 iters). LDS = 3x16 + 16 = 64 KB
// -> 2 blocks/CU (R4 lesson: 80 KB -> 1 block/CU). Regs: R2 shape = 64 arch
// VGPR + 64 AGPR at (512,2) -> no spills (R3/R5 lesson: never cap at 128).
//
// Sync = counted s_waitcnt vmcnt(N) + raw s_barrier; steady state never
// drains: end-of-iter vmcnt(2) retires A(t+1) [and B at pos==8, which is
// issued BEFORE A(t+2) there] while A(t+2) stays in flight.
//   normal iter t: top: issue A(t+2)x2. end: vmcnt(2) [A(t+1) in].
//   pos==8,cib<3:  frag reads -> lgkmcnt(0); s_barrier (old-B reads done)
//                  -> issue B(cib+1)x2, A(t+2)x2 -> MFMA -> vmcnt(2)
//                  [queue B,B,A2,A2 -> B retired, A(t+2) flying] -> barrier.
// ---------------------------------------------------------------------------
__global__ __launch_bounds__(512, 2) void conv_mfma(
    const unsigned short* __restrict__ xp,
    const unsigned short* __restrict__ wpack,
    float* __restrict__ out) {
    // A tile: [kpos(4)][o(256)][kin(8)] = 16 KB, 3-deep
    __shared__ unsigned short Al[3][4 * 256 * 8];
    // B tile: [rr(4)][kpos(4)][iw(64)][kin(8)] = 16 KB, single
    __shared__ unsigned short Bl[4 * 4 * 64 * 8];
    // total 64 KB -> 2 blocks/CU

    int tid  = threadIdx.x;
    int lane = tid & 63;
    int wid  = tid >> 6;       // 0..7
    int wm   = wid >> 1;       // 0..3  (M: 64*wm)
    int wn   = wid & 1;        // 0..1  (output row within band)
    int band = blockIdx.x;     // 0..27
    int b    = blockIdx.y;     // 0..31
    int oh0  = band * 2;

    const int klane = lane >> 4;   // k-group of this lane (0..3)
    const int fl    = lane & 15;

    f32x4 acc[4][4];
    f32x4 zero = {0.f, 0.f, 0.f, 0.f};
#pragma unroll
    for (int i = 0; i < 4; ++i)
#pragma unroll
        for (int j = 0; j < 4; ++j) acc[i][j] = zero;

    // Staging source addresses
    const unsigned short* wsrc = wpack + wid * 512 + lane * 8;
    const int s0 = wid, s1 = wid + 8;
    const int rr0 = s0 >> 2, kp0 = s0 & 3, rr1 = s1 >> 2, kp1 = s1 & 3;
    const unsigned short* bsrc0 =
        xp + (((size_t)(b * HP + oh0 + rr0)) * WP + lane) * CIN + kp0 * 8;
    const unsigned short* bsrc1 =
        xp + (((size_t)(b * HP + oh0 + rr1)) * WP + lane) * CIN + kp1 * 8;

    // ---- prologue: A(0)->Al[0], B(0)->Bl, A(1)->Al[1] ----
    gload16(wsrc, &Al[0][s0 * 512]);
    gload16(wsrc + 4096, &Al[0][s1 * 512]);
    gload16(bsrc0, &Bl[s0 * 512]);
    gload16(bsrc1, &Bl[s1 * 512]);
    gload16(wsrc + 4 * 8192, &Al[1][s0 * 512]);
    gload16(wsrc + 4 * 8192 + 4096, &Al[1][s1 * 512]);
    asm volatile("s_waitcnt vmcnt(2)" ::: "memory");   // A(0),B(0) in; A(1) flying
    __builtin_amdgcn_s_barrier();

#pragma unroll
    for (int t = 0; t < 36; ++t) {
        const int cib = t / 9, pos = t % 9;
        const int kh = pos / 3, kw = pos - kh * 3;
        const bool brestage = (pos == 8) && (cib < 3);

        // ---- top: issue A(t+2) (deferred to mid-point on B-restage iters) ----
        const int t2 = t + 2;
        const int tile2 = ((t2 % 9) * 4 + (t2 / 9));
        if (!brestage && t2 < 36) {
            gload16(wsrc + (size_t)tile2 * 8192, &Al[t2 % 3][s0 * 512]);
            gload16(wsrc + (size_t)tile2 * 8192 + 4096, &Al[t2 % 3][s1 * 512]);
        }

        // ---- fragment reads from Al[t%3], Bl ----
        bf16x8 af[4], bfr[4];
#pragma unroll
        for (int mf = 0; mf < 4; ++mf) {
            int o = wm * 64 + mf * 16 + fl;
            af[mf] = *(const bf16x8*)&Al[t % 3][(klane * 256 + o) * 8];
        }
        int rr = wn + kh;
#pragma unroll
        for (int nf = 0; nf < 4; ++nf) {
            int iw = nf * 16 + fl + kw;
            if (nf == 3) iw = iw > 63 ? 63 : iw;   // junk lanes: clamp to zero col
            bfr[nf] = *(const bf16x8*)&Bl[((rr * 4 + klane) * 64 + iw) * 8];
        }

        // ---- B restage (single buffer): old-B reads done -> overwrite ----
        if (brestage) {
            asm volatile("s_waitcnt lgkmcnt(0)" ::: "memory");  // frags in regs
            __builtin_amdgcn_s_barrier();                        // all waves done w/ Bl
            gload16(bsrc0 + (cib + 1) * 32, &Bl[s0 * 512]);      // B first...
            gload16(bsrc1 + (cib + 1) * 32, &Bl[s1 * 512]);
            gload16(wsrc + (size_t)tile2 * 8192, &Al[t2 % 3][s0 * 512]);   // ...A after
            gload16(wsrc + (size_t)tile2 * 8192 + 4096, &Al[t2 % 3][s1 * 512]);
        }

        // ---- MFMA ----
#pragma unroll
        for (int mf = 0; mf < 4; ++mf)
#pragma unroll
            for (int nf = 0; nf < 4; ++nf)
                acc[mf][nf] = __builtin_amdgcn_mfma_f32_16x16x32_bf16(
                    af[mf], bfr[nf], acc[mf][nf], 0, 0, 0);

        // ---- end sync: counted, never a steady-state drain ----
        if (t < 35) {
            if (t == 34) {
                asm volatile("s_waitcnt vmcnt(0)" ::: "memory");  // A(35) in
            } else {
                asm volatile("s_waitcnt vmcnt(2)" ::: "memory");  // A(t+1) [+B] in
            }
            __builtin_amdgcn_s_barrier();
        }
    }

    // Epilogue: C/D layout col = lane&15, row = (lane>>4)*4 + reg (m89-verified)
    int oh = oh0 + wn;
#pragma unroll
    for (int nf = 0; nf < 4; ++nf) {
        int ow = nf * 16 + fl;
        if (ow < WW) {
#pragma unroll
            for (int mf = 0; mf < 4; ++mf) {
                int ob = wm * 64 + mf * 16 + (lane >> 4) * 4;
                float* dst = out + (((size_t)b * COUT + ob) * HH + oh) * WW + ow;
#pragma unroll
                for (int r = 0; r < 4; ++r)
                    dst[(size_t)r * HH * WW] = acc[mf][nf][r];
            }
        }
    }
}

extern "C" void kernel_launch(void* const* d_in, const int* in_sizes, int n_in,
                              void* d_out, int out_size, void* d_ws, size_t ws_size,
                              hipStream_t stream) {
    const float* x    = (const float*)d_in[0];
    const float* dict = (const float*)d_in[1];
    const float* coef = (const float*)d_in[2];
    const int*   idxw = (const int*)d_in[3];
    float* out = (float*)d_out;

    unsigned short* xp    = (unsigned short*)d_ws;
    unsigned short* wpack = xp + XP_ELEMS;

    build_weight<<<dim3(COUT), dim3(256), 0, stream>>>(dict, coef, idxw, wpack);
    pack_x<<<dim3(HP, NB), dim3(256), 0, stream>>>(x, xp);
    conv_mfma<<<dim3(HH / 2, NB), dim3(512), 0, stream>>>(xp, wpack, out);
}

// Round 7
// 98.432 us; speedup vs baseline: 1.9235x; 1.0574x over previous
//
#include <hip/hip_runtime.h>
#include <hip/hip_bf16.h>
#include <stdint.h>

// Problem constants
#define NB    32    // batch
#define CIN   128
#define HH    56
#define WW    56
#define COUT  256
#define HP    58    // padded height (H+2)
#define WP    64    // padded width (56+2 -> padded to 64)

// ws layout: xp (bf16, NB*HP*WP*CIN) then wpack (bf16, 9*4*4*256*8)
#define XP_ELEMS   (NB * HP * WP * CIN)

typedef __attribute__((ext_vector_type(4))) float f32x4;
typedef __attribute__((ext_vector_type(8))) short bf16x8;

__device__ __forceinline__ unsigned short f2bf(float f) {
    union { float f; unsigned u; } v; v.f = f;
    unsigned r = v.u + 0x7FFFu + ((v.u >> 16) & 1u);
    return (unsigned short)(r >> 16);
}

__device__ __forceinline__ void gload16(const void* g, void* l) {
    __builtin_amdgcn_global_load_lds(
        (__attribute__((address_space(1))) void*)(void*)g,
        (__attribute__((address_space(3))) void*)l,
        16, 0, 0);
}

// ---------------------------------------------------------------------------
// Pass A: compose per-output-channel filters, store bf16 in wpack layout
// wpack[pos(9)][cib(4)][kpos(4)][o(256)][kin(8)], ci = cib*32 + kpos*8 + kin
// ---------------------------------------------------------------------------
__global__ __launch_bounds__(256) void build_weight(
    const float* __restrict__ dict, const float* __restrict__ coef,
    const int* __restrict__ idxw, unsigned short* __restrict__ wpack) {
    int o = blockIdx.x;
    int tid = threadIdx.x;

    // Reference dtype is int64; detect int64 vs int32 storage.
    bool mode64 = (idxw[1] == 0) && (idxw[3] == 0) && (idxw[5] == 0) &&
                  (idxw[7] == 0) && (idxw[9] == 0) && (idxw[11] == 0) &&
                  (idxw[13] == 0) && (idxw[15] == 0);

    float c[8]; int di[8];
#pragma unroll
    for (int s = 0; s < 8; ++s) {
        c[s]  = coef[o * 8 + s];
        di[s] = mode64 ? idxw[(o * 8 + s) * 2] : idxw[o * 8 + s];
    }

    for (int j = tid; j < 9 * 128; j += 256) {
        int pos = j >> 7;          // 0..8
        int ci  = j & 127;
        int kh = pos / 3, kw = pos - kh * 3;
        float v = 0.f;
#pragma unroll
        for (int s = 0; s < 8; ++s)
            v += c[s] * dict[((di[s] * CIN + ci) * 3 + kh) * 3 + kw];
        int cib = ci >> 5, kpos = (ci >> 3) & 3, kin = ci & 7;
        wpack[((((pos * 4 + cib) * 4 + kpos) * COUT + o) << 3) + kin] = f2bf(v);
    }
}

// ---------------------------------------------------------------------------
// Pass B: NCHW fp32 -> zero-padded NHWC bf16, vectorized short8 stores
// xp[b][ih(58)][iw(64)][ci(128)]; valid x at ih in [1,56], iw in [1,56]
// ---------------------------------------------------------------------------
__global__ __launch_bounds__(256) void pack_x(
    const float* __restrict__ x, unsigned short* __restrict__ xp) {
    int ih = blockIdx.x;   // 0..57
    int b  = blockIdx.y;
    int tid = threadIdx.x;
    size_t obase = ((size_t)(b * HP + ih)) * WP * CIN;
    bf16x8* outv = (bf16x8*)(xp + obase);   // 1024 vectors of 8 bf16

    if (ih == 0 || ih == HP - 1) {
        bf16x8 z = {0, 0, 0, 0, 0, 0, 0, 0};
        for (int e = tid; e < WP * CIN / 8; e += 256) outv[e] = z;
        return;
    }

    __shared__ float xs[CIN][WW + 1];   // +1 pad: odd stride
    int h = ih - 1;
    for (int e = tid; e < CIN * WW; e += 256) {
        int ci = e / WW, w = e - ci * WW;
        xs[ci][w] = x[(((size_t)b * CIN + ci) * HH + h) * WW + w];
    }
    __syncthreads();
    for (int ch = tid; ch < WP * CIN / 8; ch += 256) {
        int iw = ch >> 4;            // 0..63
        int cb = (ch & 15) << 3;     // ci base, 0..120
        bf16x8 v = {0, 0, 0, 0, 0, 0, 0, 0};
        if (iw >= 1 && iw <= WW) {
#pragma unroll
            for (int j = 0; j < 8; ++j)
                v[j] = (short)f2bf(xs[cb + j][iw - 1]);
        }
        outv[ch] = v;
    }
}

// ---------------------------------------------------------------------------
// Main: implicit-GEMM conv.  Block = 256 Cout x 2 output rows (one b).
// 512 threads = 8 waves; wave grid 4(M) x 2(N); wave tile 64x64.
//
// Structure = R2's proven 64-arch-reg / 66 KB / 2-blocks-per-CU envelope
// (R3/R5 lesson: never cap regs below 64 arch + 64 acc; R4/R6 lesson:
// LDS > ~76 KB or arch regs > 64 -> 1 block/CU, loses more than any
// pipeline gains). Three zero-register changes on top:
//  1. B(cib+1) staged at pos==7 AFTER the A-pair; that iteration waits
//     vmcnt(2) (A in, B flying) so B gets ~2 iterations (~700 cyc) of
//     flight before the natural pos8 drain -> HBM latency covered.
//     All other iterations wait vmcnt(0) (same as __syncthreads; with
//     distance-1 A prefetch the just-issued A pair is youngest, so a
//     counted wait would be vmcnt(0) anyway).
//  2. s_setprio(1) around the MFMA cluster (T5) - two drifting blocks
//     per CU give the scheduler something to arbitrate.
//  3. XCD-bijective swizzle of the 896-block grid (896 = 8*112): each
//     XCD works 4 consecutive batches -> xp slice (~3.8 MB) + wpack
//     (0.6 MB) fit its 4 MB L2 -> B staging misses become L2 hits.
// ---------------------------------------------------------------------------
__global__ __launch_bounds__(512, 2) void conv_mfma(
    const unsigned short* __restrict__ xp,
    const unsigned short* __restrict__ wpack,
    float* __restrict__ out) {
    // B tile: [rr(4)][kpos(4)][iw(64)][kin(8)]  (+pad: taps read iw up to 65)
    __shared__ unsigned short Bl[2][4 * 4 * 64 * 8 + 64];
    // A tile: [kpos(4)][o(256)][kin(8)]
    __shared__ unsigned short Al[2][4 * 256 * 8];

    int tid  = threadIdx.x;
    int lane = tid & 63;
    int wid  = tid >> 6;       // 0..7
    int wm   = wid >> 1;       // 0..3  (M: 64*wm)
    int wn   = wid & 1;        // 0..1  (output row within band)

    // XCD-bijective swizzle: flat 0..895 -> xcd chunk of 112 -> (b, band)
    int flat = blockIdx.x;
    int swz  = (flat & 7) * 112 + (flat >> 3);
    int b    = swz / 28;       // 0..31
    int band = swz % 28;       // 0..27
    int oh0  = band * 2;

    const int klane = lane >> 4;   // k-group of this lane (0..3)
    const int fl    = lane & 15;

    f32x4 acc[4][4];
    f32x4 zero = {0.f, 0.f, 0.f, 0.f};
#pragma unroll
    for (int i = 0; i < 4; ++i)
#pragma unroll
        for (int j = 0; j < 4; ++j) acc[i][j] = zero;

    // ---- prologue: stage A(t=0) -> Al[0], B(cib=0) -> Bl[0] ----
#pragma unroll
    for (int tt = 0; tt < 2; ++tt) {
        int s = wid + tt * 8;
        const unsigned short* srcA = wpack + (size_t)s * 512 + lane * 8;
        gload16(srcA, &Al[0][s * 512]);
        int rr = s >> 2, kpos = s & 3;
        const unsigned short* srcB =
            xp + (((size_t)(b * HP + oh0 + rr)) * WP + lane) * CIN + kpos * 8;
        gload16(srcB, &Bl[0][s * 512]);
    }
    __syncthreads();

    int abuf = 0;
#pragma unroll
    for (int cib = 0; cib < 4; ++cib) {
        const int bbuf = cib & 1;
#pragma unroll
        for (int pos = 0; pos < 9; ++pos) {
            const int t = cib * 9 + pos;
            const int kh = pos / 3, kw = pos - kh * 3;
            const bool bstage = (pos == 7) && (cib < 3);

            // ---- 1. prefetch A(t+1) into Al[abuf^1] ----
            if (t < 35) {
                const int c1 = (t + 1) / 9, p1 = (t + 1) % 9;
#pragma unroll
                for (int tt = 0; tt < 2; ++tt) {
                    int s = wid + tt * 8;
                    const unsigned short* srcA =
                        wpack + (size_t)(p1 * 4 + c1) * 8192 + s * 512 + lane * 8;
                    gload16(srcA, &Al[abuf ^ 1][s * 512]);
                }
            }
            // ---- 2. prefetch B(cib+1) AFTER A (pos==7 -> ~2 iters flight) ----
            if (bstage) {
#pragma unroll
                for (int tt = 0; tt < 2; ++tt) {
                    int s = wid + tt * 8;
                    int rr = s >> 2, kpos = s & 3;
                    gload16(xp + (((size_t)(b * HP + oh0 + rr)) * WP + lane) * CIN +
                                (cib + 1) * 32 + kpos * 8,
                            &Bl[bbuf ^ 1][s * 512]);
                }
            }

            // ---- 3. fragment reads from Al[abuf], Bl[bbuf] ----
            bf16x8 af[4], bfr[4];
#pragma unroll
            for (int mf = 0; mf < 4; ++mf) {
                int o = wm * 64 + mf * 16 + fl;
                af[mf] = *(const bf16x8*)&Al[abuf][(klane * 256 + o) * 8];
            }
            int rr = wn + kh;
#pragma unroll
            for (int nf = 0; nf < 4; ++nf) {
                int iw = nf * 16 + fl + kw;   // may reach 65 for junk cols
                bfr[nf] = *(const bf16x8*)&Bl[bbuf][((rr * 4 + klane) * 64 + iw) * 8];
            }

            // ---- 4. MFMA (priority-boosted) ----
            __builtin_amdgcn_s_setprio(1);
#pragma unroll
            for (int mf = 0; mf < 4; ++mf)
#pragma unroll
                for (int nf = 0; nf < 4; ++nf)
                    acc[mf][nf] = __builtin_amdgcn_mfma_f32_16x16x32_bf16(
                        af[mf], bfr[nf], acc[mf][nf], 0, 0, 0);
            __builtin_amdgcn_s_setprio(0);

            // ---- 5. sync: vmcnt(2) only where B is in flight ----
            if (t < 35) {
                if (bstage) {
                    asm volatile("s_waitcnt vmcnt(2) lgkmcnt(0)" ::: "memory");
                } else {
                    asm volatile("s_waitcnt vmcnt(0) lgkmcnt(0)" ::: "memory");
                }
                __builtin_amdgcn_s_barrier();
            }
            abuf ^= 1;
        }
    }

    // Epilogue: C/D layout col = lane&15, row = (lane>>4)*4 + reg (m89-verified)
    int oh = oh0 + wn;
#pragma unroll
    for (int nf = 0; nf < 4; ++nf) {
        int ow = nf * 16 + fl;
        if (ow < WW) {
#pragma unroll
            for (int mf = 0; mf < 4; ++mf) {
                int ob = wm * 64 + mf * 16 + (lane >> 4) * 4;
                float* dst = out + (((size_t)b * COUT + ob) * HH + oh) * WW + ow;
#pragma unroll
                for (int r = 0; r < 4; ++r)
                    dst[(size_t)r * HH * WW] = acc[mf][nf][r];
            }
        }
    }
}

extern "C" void kernel_launch(void* const* d_in, const int* in_sizes, int n_in,
                              void* d_out, int out_size, void* d_ws, size_t ws_size,
                              hipStream_t stream) {
    const float* x    = (const float*)d_in[0];
    const float* dict = (const float*)d_in[1];
    const float* coef = (const float*)d_in[2];
    const int*   idxw = (const int*)d_in[3];
    float* out = (float*)d_out;

    unsigned short* xp    = (unsigned short*)d_ws;
    unsigned short* wpack = xp + XP_ELEMS;

    build_weight<<<dim3(COUT), dim3(256), 0, stream>>>(dict, coef, idxw, wpack);
    pack_x<<<dim3(HP, NB), dim3(256), 0, stream>>>(x, xp);
    conv_mfma<<<dim3(28 * NB), dim3(512), 0, stream>>>(xp, wpack, out);
}

// Round 8
// 95.842 us; speedup vs baseline: 1.9755x; 1.0270x over previous
//
#include <hip/hip_runtime.h>
#include <hip/hip_bf16.h>
#include <stdint.h>

// Problem constants
#define NB    32    // batch
#define CIN   128
#define HH    56
#define WW    56
#define COUT  256
#define HP    58    // padded height (H+2)
#define WP    64    // padded width (56+2 -> padded to 64)

// ws layout: xp (bf16, NB*HP*WP*CIN) then wpack (bf16, 9*4*4*256*8)
#define XP_ELEMS   (NB * HP * WP * CIN)

typedef __attribute__((ext_vector_type(4))) float f32x4;
typedef __attribute__((ext_vector_type(8))) short bf16x8;

__device__ __forceinline__ unsigned short f2bf(float f) {
    union { float f; unsigned u; } v; v.f = f;
    unsigned r = v.u + 0x7FFFu + ((v.u >> 16) & 1u);
    return (unsigned short)(r >> 16);
}

__device__ __forceinline__ void gload16(const void* g, void* l) {
    __builtin_amdgcn_global_load_lds(
        (__attribute__((address_space(1))) void*)(void*)g,
        (__attribute__((address_space(3))) void*)l,
        16, 0, 0);
}

// ---------------------------------------------------------------------------
// Pass A: compose per-output-channel filters, store bf16 in wpack layout
// wpack[pos(9)][cib(4)][kpos(4)][o(256)][kin(8)], ci = cib*32 + kpos*8 + kin
// ---------------------------------------------------------------------------
__global__ __launch_bounds__(256) void build_weight(
    const float* __restrict__ dict, const float* __restrict__ coef,
    const int* __restrict__ idxw, unsigned short* __restrict__ wpack) {
    int o = blockIdx.x;
    int tid = threadIdx.x;

    // Reference dtype is int64; detect int64 vs int32 storage.
    bool mode64 = (idxw[1] == 0) && (idxw[3] == 0) && (idxw[5] == 0) &&
                  (idxw[7] == 0) && (idxw[9] == 0) && (idxw[11] == 0) &&
                  (idxw[13] == 0) && (idxw[15] == 0);

    float c[8]; int di[8];
#pragma unroll
    for (int s = 0; s < 8; ++s) {
        c[s]  = coef[o * 8 + s];
        di[s] = mode64 ? idxw[(o * 8 + s) * 2] : idxw[o * 8 + s];
    }

    for (int j = tid; j < 9 * 128; j += 256) {
        int pos = j >> 7;          // 0..8
        int ci  = j & 127;
        int kh = pos / 3, kw = pos - kh * 3;
        float v = 0.f;
#pragma unroll
        for (int s = 0; s < 8; ++s)
            v += c[s] * dict[((di[s] * CIN + ci) * 3 + kh) * 3 + kw];
        int cib = ci >> 5, kpos = (ci >> 3) & 3, kin = ci & 7;
        wpack[((((pos * 4 + cib) * 4 + kpos) * COUT + o) << 3) + kin] = f2bf(v);
    }
}

// ---------------------------------------------------------------------------
// Pass B: NCHW fp32 -> zero-padded NHWC bf16, vectorized short8 stores
// xp[b][ih(58)][iw(64)][ci(128)]; valid x at ih in [1,56], iw in [1,56]
// ---------------------------------------------------------------------------
__global__ __launch_bounds__(256) void pack_x(
    const float* __restrict__ x, unsigned short* __restrict__ xp) {
    int ih = blockIdx.x;   // 0..57
    int b  = blockIdx.y;
    int tid = threadIdx.x;
    size_t obase = ((size_t)(b * HP + ih)) * WP * CIN;
    bf16x8* outv = (bf16x8*)(xp + obase);   // 1024 vectors of 8 bf16

    if (ih == 0 || ih == HP - 1) {
        bf16x8 z = {0, 0, 0, 0, 0, 0, 0, 0};
        for (int e = tid; e < WP * CIN / 8; e += 256) outv[e] = z;
        return;
    }

    __shared__ float xs[CIN][WW + 1];   // +1 pad: odd stride
    int h = ih - 1;
    for (int e = tid; e < CIN * WW; e += 256) {
        int ci = e / WW, w = e - ci * WW;
        xs[ci][w] = x[(((size_t)b * CIN + ci) * HH + h) * WW + w];
    }
    __syncthreads();
    for (int ch = tid; ch < WP * CIN / 8; ch += 256) {
        int iw = ch >> 4;            // 0..63
        int cb = (ch & 15) << 3;     // ci base, 0..120
        bf16x8 v = {0, 0, 0, 0, 0, 0, 0, 0};
        if (iw >= 1 && iw <= WW) {
#pragma unroll
            for (int j = 0; j < 8; ++j)
                v[j] = (short)f2bf(xs[cb + j][iw - 1]);
        }
        outv[ch] = v;
    }
}

// ---------------------------------------------------------------------------
// Main: implicit-GEMM conv.  Block = 256 Cout x 2 output rows (one b).
// 512 threads = 8 waves; wave grid 4(M) x 2(N); wave tile 64x64.
//
// BARRIER-MINIMAL structure (R7 post-mortem: 36 block-wide vmcnt(0) drains
// per block were the 9%-of-peak floor; every deeper LDS pipeline blew the
// 128-unified-reg / 64KB envelope):
//  - A (weights) read DIRECTLY global->regs per tap: wpack layout ==
//    fragment layout, wpack is L2-hot (576 KB, XCD-swizzled grid), and the
//    wn-pair's duplicate read hits L1. A needs NO barrier, NO LDS; its
//    latency is per-wave and hidden by the other drifting waves per SIMD.
//  - B (x tile) in LDS, double-buffered, restaged once per cib (9 taps)
//    via global_load_lds -> only THREE __syncthreads per block; within a
//    cib the 8 waves run fully unsynchronized.
//  - (512,2): R5 lesson - the (512,4) 128-reg cap forced acc spills
//    (+400 MB scratch). Body = acc 64 AGPR + af/bfr 32 + addr -> ~110.
//  - LDS = 2 x 16.1 KB = 33 KB -> 2 blocks/CU at regs <= 128.
// ---------------------------------------------------------------------------
__global__ __launch_bounds__(512, 2) void conv_mfma(
    const unsigned short* __restrict__ xp,
    const unsigned short* __restrict__ wpack,
    float* __restrict__ out) {
    // B tile: [rr(4)][kpos(4)][iw(64)][kin(8)]  (+pad: taps read iw up to 65)
    __shared__ unsigned short Bl[2][4 * 4 * 64 * 8 + 64];

    int tid  = threadIdx.x;
    int lane = tid & 63;
    int wid  = tid >> 6;       // 0..7
    int wm   = wid >> 1;       // 0..3  (M: 64*wm)
    int wn   = wid & 1;        // 0..1  (output row within band)

    // XCD-bijective swizzle: flat 0..895 -> xcd chunk of 112 -> (b, band)
    int flat = blockIdx.x;
    int swz  = (flat & 7) * 112 + (flat >> 3);
    int b    = swz / 28;       // 0..31
    int band = swz % 28;       // 0..27
    int oh0  = band * 2;

    const int klane = lane >> 4;   // k-group of this lane (0..3)
    const int fl    = lane & 15;

    f32x4 acc[4][4];
    f32x4 zero = {0.f, 0.f, 0.f, 0.f};
#pragma unroll
    for (int i = 0; i < 4; ++i)
#pragma unroll
        for (int j = 0; j < 4; ++j) acc[i][j] = zero;

    // Per-lane A-fragment base (bf16 elems): o = wm*64 + mf*16 + fl
    // frag addr = wpack + tile*8192 + (klane*256 + o)*8
    const unsigned short* ap = wpack + ((size_t)klane * 256 + wm * 64 + fl) * 8;

    // B staging source addresses (two 1-KB slices per wave)
    const int s0 = wid, s1 = wid + 8;
    const int rr0 = s0 >> 2, kp0 = s0 & 3, rr1 = s1 >> 2, kp1 = s1 & 3;
    const unsigned short* bsrc0 =
        xp + (((size_t)(b * HP + oh0 + rr0)) * WP + lane) * CIN + kp0 * 8;
    const unsigned short* bsrc1 =
        xp + (((size_t)(b * HP + oh0 + rr1)) * WP + lane) * CIN + kp1 * 8;

    // ---- prologue: stage B(cib=0) ----
    gload16(bsrc0, &Bl[0][s0 * 512]);
    gload16(bsrc1, &Bl[0][s1 * 512]);
    __syncthreads();

#pragma unroll
    for (int cib = 0; cib < 4; ++cib) {
        const int bbuf = cib & 1;

        // ---- stage B(cib+1) into the other buffer: 9 taps of slack ----
        if (cib < 3) {
            gload16(bsrc0 + (cib + 1) * 32, &Bl[bbuf ^ 1][s0 * 512]);
            gload16(bsrc1 + (cib + 1) * 32, &Bl[bbuf ^ 1][s1 * 512]);
        }

#pragma unroll
        for (int pos = 0; pos < 9; ++pos) {
            const int kh = pos / 3, kw = pos - kh * 3;
            const int tile = pos * 4 + cib;

            // ---- A fragments: direct global->reg from L2-hot wpack ----
            bf16x8 af[4];
#pragma unroll
            for (int mf = 0; mf < 4; ++mf)
                af[mf] = *(const bf16x8*)(ap + (size_t)tile * 8192 + mf * 128);

            // ---- B fragments from LDS ----
            bf16x8 bfr[4];
            int rr = wn + kh;
#pragma unroll
            for (int nf = 0; nf < 4; ++nf) {
                int iw = nf * 16 + fl + kw;   // may reach 65 (junk cols, padded)
                bfr[nf] = *(const bf16x8*)&Bl[bbuf][((rr * 4 + klane) * 64 + iw) * 8];
            }

            // ---- MFMA (priority-boosted) ----
            __builtin_amdgcn_s_setprio(1);
#pragma unroll
            for (int mf = 0; mf < 4; ++mf)
#pragma unroll
                for (int nf = 0; nf < 4; ++nf)
                    acc[mf][nf] = __builtin_amdgcn_mfma_f32_16x16x32_bf16(
                        af[mf], bfr[nf], acc[mf][nf], 0, 0, 0);
            __builtin_amdgcn_s_setprio(0);
        }

        // ---- single barrier per cib: next B visible to all waves ----
        if (cib < 3) __syncthreads();
    }

    // Epilogue: C/D layout col = lane&15, row = (lane>>4)*4 + reg (m89-verified)
    int oh = oh0 + wn;
#pragma unroll
    for (int nf = 0; nf < 4; ++nf) {
        int ow = nf * 16 + fl;
        if (ow < WW) {
#pragma unroll
            for (int mf = 0; mf < 4; ++mf) {
                int ob = wm * 64 + mf * 16 + (lane >> 4) * 4;
                float* dst = out + (((size_t)b * COUT + ob) * HH + oh) * WW + ow;
#pragma unroll
                for (int r = 0; r < 4; ++r)
                    dst[(size_t)r * HH * WW] = acc[mf][nf][r];
            }
        }
    }
}

extern "C" void kernel_launch(void* const* d_in, const int* in_sizes, int n_in,
                              void* d_out, int out_size, void* d_ws, size_t ws_size,
                              hipStream_t stream) {
    const float* x    = (const float*)d_in[0];
    const float* dict = (const float*)d_in[1];
    const float* coef = (const float*)d_in[2];
    const int*   idxw = (const int*)d_in[3];
    float* out = (float*)d_out;

    unsigned short* xp    = (unsigned short*)d_ws;
    unsigned short* wpack = xp + XP_ELEMS;

    build_weight<<<dim3(COUT), dim3(256), 0, stream>>>(dict, coef, idxw, wpack);
    pack_x<<<dim3(HP, NB), dim3(256), 0, stream>>>(x, xp);
    conv_mfma<<<dim3(28 * NB), dim3(512), 0, stream>>>(xp, wpack, out);
}

// Round 9
// 91.695 us; speedup vs baseline: 2.0648x; 1.0452x over previous
//
#include <hip/hip_runtime.h>
#include <hip/hip_bf16.h>
#include <stdint.h>

// Problem constants
#define NB    32    // batch
#define CIN   128
#define HH    56
#define WW    56
#define COUT  256
#define HP    58    // padded height (H+2)
#define WP    64    // padded width (56+2 -> padded to 64)

// ws layout: xp (bf16, NB*HP*WP*CIN) then wpack (bf16, 9*4*4*256*8)
#define XP_ELEMS   (NB * HP * WP * CIN)

typedef __attribute__((ext_vector_type(4))) float f32x4;
typedef __attribute__((ext_vector_type(8))) short bf16x8;

__device__ __forceinline__ unsigned short f2bf(float f) {
    union { float f; unsigned u; } v; v.f = f;
    unsigned r = v.u + 0x7FFFu + ((v.u >> 16) & 1u);
    return (unsigned short)(r >> 16);
}

__device__ __forceinline__ void gload16(const void* g, void* l) {
    __builtin_amdgcn_global_load_lds(
        (__attribute__((address_space(1))) void*)(void*)g,
        (__attribute__((address_space(3))) void*)l,
        16, 0, 0);
}

// ---------------------------------------------------------------------------
// Pass A: compose per-output-channel filters, store bf16 in wpack layout
// wpack[pos(9)][cib(4)][kpos(4)][o(256)][kin(8)], ci = cib*32 + kpos*8 + kin
// ---------------------------------------------------------------------------
__global__ __launch_bounds__(256) void build_weight(
    const float* __restrict__ dict, const float* __restrict__ coef,
    const int* __restrict__ idxw, unsigned short* __restrict__ wpack) {
    int o = blockIdx.x;
    int tid = threadIdx.x;

    // Reference dtype is int64; detect int64 vs int32 storage.
    bool mode64 = (idxw[1] == 0) && (idxw[3] == 0) && (idxw[5] == 0) &&
                  (idxw[7] == 0) && (idxw[9] == 0) && (idxw[11] == 0) &&
                  (idxw[13] == 0) && (idxw[15] == 0);

    float c[8]; int di[8];
#pragma unroll
    for (int s = 0; s < 8; ++s) {
        c[s]  = coef[o * 8 + s];
        di[s] = mode64 ? idxw[(o * 8 + s) * 2] : idxw[o * 8 + s];
    }

    for (int j = tid; j < 9 * 128; j += 256) {
        int pos = j >> 7;          // 0..8
        int ci  = j & 127;
        int kh = pos / 3, kw = pos - kh * 3;
        float v = 0.f;
#pragma unroll
        for (int s = 0; s < 8; ++s)
            v += c[s] * dict[((di[s] * CIN + ci) * 3 + kh) * 3 + kw];
        int cib = ci >> 5, kpos = (ci >> 3) & 3, kin = ci & 7;
        wpack[((((pos * 4 + cib) * 4 + kpos) * COUT + o) << 3) + kin] = f2bf(v);
    }
}

// ---------------------------------------------------------------------------
// Pass B: NCHW fp32 -> zero-padded NHWC bf16, vectorized short8 stores
// xp[b][ih(58)][iw(64)][ci(128)]; valid x at ih in [1,56], iw in [1,56]
// ---------------------------------------------------------------------------
__global__ __launch_bounds__(256) void pack_x(
    const float* __restrict__ x, unsigned short* __restrict__ xp) {
    int ih = blockIdx.x;   // 0..57
    int b  = blockIdx.y;
    int tid = threadIdx.x;
    size_t obase = ((size_t)(b * HP + ih)) * WP * CIN;
    bf16x8* outv = (bf16x8*)(xp + obase);   // 1024 vectors of 8 bf16

    if (ih == 0 || ih == HP - 1) {
        bf16x8 z = {0, 0, 0, 0, 0, 0, 0, 0};
        for (int e = tid; e < WP * CIN / 8; e += 256) outv[e] = z;
        return;
    }

    __shared__ float xs[CIN][WW + 1];   // +1 pad: odd stride
    int h = ih - 1;
    for (int e = tid; e < CIN * WW; e += 256) {
        int ci = e / WW, w = e - ci * WW;
        xs[ci][w] = x[(((size_t)b * CIN + ci) * HH + h) * WW + w];
    }
    __syncthreads();
    for (int ch = tid; ch < WP * CIN / 8; ch += 256) {
        int iw = ch >> 4;            // 0..63
        int cb = (ch & 15) << 3;     // ci base, 0..120
        bf16x8 v = {0, 0, 0, 0, 0, 0, 0, 0};
        if (iw >= 1 && iw <= WW) {
#pragma unroll
            for (int j = 0; j < 8; ++j)
                v[j] = (short)f2bf(xs[cb + j][iw - 1]);
        }
        outv[ch] = v;
    }
}

// ---------------------------------------------------------------------------
// Main: implicit-GEMM conv.
// R9 structure (R8 post-mortem: per-wave tap latency ~2000+ cyc, not hidden
// at 4 waves/SIMD with a 128-reg cap blocking register prefetch):
//  - Block = 256 threads = 4 waves = 256 Cout x ONE output row.
//    4-wave blocks land exactly 1 wave/SIMD -> 3 blocks/CU co-schedule as
//    a clean 3 waves/SIMD at <=170 regs (launch_bounds(256,3)).
//  - Wave = 64 Cout x 64 cols, acc[4][4] (64 AGPR) as before.
//  - A fragments: direct global->reg from L2-hot wpack with EXPLICIT
//    distance-1 register prefetch (afn[4], +16 regs) -> the af->MFMA
//    dependency chain spans a full tap of independent work.
//  - B: 3-row tile [rr(3)][kpos(4)][iw(64)][kin(8)] = 12 KB, double-
//    buffered, staged once per cib -> 3 barriers/block.
//  - cib loop dynamic (#pragma unroll 1): hot code ~7 KB, protects I-cache
//    (R2-R8 fully unrolled 36 taps = ~26 KB bodies).
//  - Grid 1792 = 7 x 256 CUs, perfectly balanced; XCD swizzle gives each
//    XCD 4 batches (xp slice ~3.8 MB + wpack 0.6 MB resident in its L2).
// ---------------------------------------------------------------------------
__global__ __launch_bounds__(256, 3) void conv_mfma(
    const unsigned short* __restrict__ xp,
    const unsigned short* __restrict__ wpack,
    float* __restrict__ out) {
    // B tile: chunks (rr*4+kpos)*64+iw of 16B; 768 chunks + pad for kw spill
    __shared__ unsigned short Bl[2][3 * 4 * 64 * 8 + 128];

    int tid  = threadIdx.x;
    int lane = tid & 63;
    int wid  = tid >> 6;       // 0..3 = wm (Cout slice of 64)

    // XCD-bijective swizzle: 1792 = 8 * 224; each XCD gets 4 consecutive b's
    int flat = blockIdx.x;
    int swz  = (flat & 7) * 224 + (flat >> 3);
    int b    = swz / 56;       // 0..31
    int oh   = swz % 56;       // output row

    const int klane = lane >> 4;   // k-group (0..3)
    const int fl    = lane & 15;

    f32x4 acc[4][4];
    f32x4 zero = {0.f, 0.f, 0.f, 0.f};
#pragma unroll
    for (int i = 0; i < 4; ++i)
#pragma unroll
        for (int j = 0; j < 4; ++j) acc[i][j] = zero;

    // Per-lane A-fragment base: af(tile,mf) at ap0 + tile*8192 + mf*128 (elems)
    const unsigned short* ap0 = wpack + ((size_t)klane * 256 + wid * 64 + fl) * 8;

    // B staging: thread stages chunks (rr=k, kpos=wid, iw=lane), k=0..2
    // src row stride = WP*CIN = 8192 elems; cib adds 32 elems
    const unsigned short* bs =
        xp + (((size_t)(b * HP + oh)) * WP + lane) * CIN + wid * 8;

    // ---- prologue: stage B(cib0); preload A(tile 0) ----
#pragma unroll
    for (int k = 0; k < 3; ++k)
        gload16(bs + (size_t)k * 8192, &Bl[0][(k * 256 + wid * 64) * 8]);

    bf16x8 afc[4], afn[4];
#pragma unroll
    for (int mf = 0; mf < 4; ++mf)
        afc[mf] = *(const bf16x8*)(ap0 + mf * 128);
    __syncthreads();

    const unsigned short* apc = ap0;   // += 8192 elems per cib
    const unsigned short* bsc = bs;    // += 32 elems per cib

#pragma unroll 1
    for (int cib = 0; cib < 4; ++cib) {
        const int bbuf = cib & 1;

        // ---- stage B(cib+1) into other buffer: 9 taps of slack ----
        if (cib < 3) {
#pragma unroll
            for (int k = 0; k < 3; ++k)
                gload16(bsc + 32 + (size_t)k * 8192,
                        &Bl[bbuf ^ 1][(k * 256 + wid * 64) * 8]);
        }

#pragma unroll
        for (int pos = 0; pos < 9; ++pos) {
            const int kh = pos / 3, kw = pos - kh * 3;

            // ---- prefetch A(next tap) into afn (distance-1 reg pipeline) ----
            if (pos < 8) {
#pragma unroll
                for (int mf = 0; mf < 4; ++mf)
                    afn[mf] = *(const bf16x8*)(apc + (pos + 1) * 32768 + mf * 128);
            } else if (cib < 3) {
#pragma unroll
                for (int mf = 0; mf < 4; ++mf)
                    afn[mf] = *(const bf16x8*)(apc + 8192 + mf * 128);
            }

            // ---- B fragments from LDS ----
            bf16x8 bfr[4];
#pragma unroll
            for (int nf = 0; nf < 4; ++nf) {
                int ch = kh * 256 + klane * 64 + nf * 16 + fl + kw;  // junk lanes spill into pad
                bfr[nf] = *(const bf16x8*)&Bl[bbuf][ch * 8];
            }

            // ---- MFMA on afc (loaded a full tap ago) ----
            __builtin_amdgcn_s_setprio(1);
#pragma unroll
            for (int mf = 0; mf < 4; ++mf)
#pragma unroll
                for (int nf = 0; nf < 4; ++nf)
                    acc[mf][nf] = __builtin_amdgcn_mfma_f32_16x16x32_bf16(
                        afc[mf], bfr[nf], acc[mf][nf], 0, 0, 0);
            __builtin_amdgcn_s_setprio(0);

            // rotate the register pipeline
#pragma unroll
            for (int mf = 0; mf < 4; ++mf) afc[mf] = afn[mf];
        }

        apc += 8192;
        bsc += 32;
        if (cib < 3) __syncthreads();   // next B resident (9 taps of flight)
    }

    // Epilogue: C/D layout col = lane&15, row = (lane>>4)*4 + reg (m89-verified)
#pragma unroll
    for (int nf = 0; nf < 4; ++nf) {
        int ow = nf * 16 + fl;
        if (ow < WW) {
#pragma unroll
            for (int mf = 0; mf < 4; ++mf) {
                int ob = wid * 64 + mf * 16 + (lane >> 4) * 4;
                float* dst = out + (((size_t)b * COUT + ob) * HH + oh) * WW + ow;
#pragma unroll
                for (int r = 0; r < 4; ++r)
                    dst[(size_t)r * HH * WW] = acc[mf][nf][r];
            }
        }
    }
}

extern "C" void kernel_launch(void* const* d_in, const int* in_sizes, int n_in,
                              void* d_out, int out_size, void* d_ws, size_t ws_size,
                              hipStream_t stream) {
    const float* x    = (const float*)d_in[0];
    const float* dict = (const float*)d_in[1];
    const float* coef = (const float*)d_in[2];
    const int*   idxw = (const int*)d_in[3];
    float* out = (float*)d_out;

    unsigned short* xp    = (unsigned short*)d_ws;
    unsigned short* wpack = xp + XP_ELEMS;

    build_weight<<<dim3(COUT), dim3(256), 0, stream>>>(dict, coef, idxw, wpack);
    pack_x<<<dim3(HP, NB), dim3(256), 0, stream>>>(x, xp);
    conv_mfma<<<dim3(NB * 56), dim3(256), 0, stream>>>(xp, wpack, out);
}

// Round 10
// 90.435 us; speedup vs baseline: 2.0936x; 1.0139x over previous
//
#include <hip/hip_runtime.h>
#include <hip/hip_bf16.h>
#include <stdint.h>

// Problem constants
#define NB    32    // batch
#define CIN   128
#define HH    56
#define WW    56
#define COUT  256
#define HP    58    // padded height (H+2)
#define WP    64    // padded width (56+2 -> padded to 64)

// ws layout: xp (bf16, NB*HP*WP*CIN) then wpack (bf16, 9*4*4*256*8)
#define XP_ELEMS   (NB * HP * WP * CIN)

typedef __attribute__((ext_vector_type(4))) float f32x4;
typedef __attribute__((ext_vector_type(8))) short bf16x8;

__device__ __forceinline__ unsigned short f2bf(float f) {
    union { float f; unsigned u; } v; v.f = f;
    unsigned r = v.u + 0x7FFFu + ((v.u >> 16) & 1u);
    return (unsigned short)(r >> 16);
}

__device__ __forceinline__ void gload16(const void* g, void* l) {
    __builtin_amdgcn_global_load_lds(
        (__attribute__((address_space(1))) void*)(void*)g,
        (__attribute__((address_space(3))) void*)l,
        16, 0, 0);
}

// ---------------------------------------------------------------------------
// Fused prep: blocks [0,256) compose weights; blocks [256,256+HP*NB) pack x.
// The 256 tiny build blocks overlap with the BW-bound pack blocks.
// ---------------------------------------------------------------------------
__global__ __launch_bounds__(256) void prep(
    const float* __restrict__ x, const float* __restrict__ dict,
    const float* __restrict__ coef, const int* __restrict__ idxw,
    unsigned short* __restrict__ wpack, unsigned short* __restrict__ xp) {
    int tid = threadIdx.x;

    if (blockIdx.x < COUT) {
        // ---- build_weight: wpack[pos][cib][kpos][o][kin] ----
        int o = blockIdx.x;
        // Reference dtype is int64; detect int64 vs int32 storage.
        bool mode64 = (idxw[1] == 0) && (idxw[3] == 0) && (idxw[5] == 0) &&
                      (idxw[7] == 0) && (idxw[9] == 0) && (idxw[11] == 0) &&
                      (idxw[13] == 0) && (idxw[15] == 0);
        float c[8]; int di[8];
#pragma unroll
        for (int s = 0; s < 8; ++s) {
            c[s]  = coef[o * 8 + s];
            di[s] = mode64 ? idxw[(o * 8 + s) * 2] : idxw[o * 8 + s];
        }
        for (int j = tid; j < 9 * 128; j += 256) {
            int pos = j >> 7;          // 0..8
            int ci  = j & 127;
            int kh = pos / 3, kw = pos - kh * 3;
            float v = 0.f;
#pragma unroll
            for (int s = 0; s < 8; ++s)
                v += c[s] * dict[((di[s] * CIN + ci) * 3 + kh) * 3 + kw];
            int cib = ci >> 5, kpos = (ci >> 3) & 3, kin = ci & 7;
            wpack[((((pos * 4 + cib) * 4 + kpos) * COUT + o) << 3) + kin] = f2bf(v);
        }
        return;
    }

    // ---- pack_x: NCHW fp32 -> zero-padded NHWC bf16 ----
    int idx = blockIdx.x - COUT;
    int ih = idx % HP;         // 0..57
    int b  = idx / HP;         // 0..31
    size_t obase = ((size_t)(b * HP + ih)) * WP * CIN;
    bf16x8* outv = (bf16x8*)(xp + obase);   // 1024 vectors of 8 bf16

    if (ih == 0 || ih == HP - 1) {
        bf16x8 z = {0, 0, 0, 0, 0, 0, 0, 0};
        for (int e = tid; e < WP * CIN / 8; e += 256) outv[e] = z;
        return;
    }

    __shared__ float xs[CIN][WW + 1];   // +1 pad: odd stride
    int h = ih - 1;
    for (int e = tid; e < CIN * WW; e += 256) {
        int ci = e / WW, w = e - ci * WW;
        xs[ci][w] = x[(((size_t)b * CIN + ci) * HH + h) * WW + w];
    }
    __syncthreads();
    for (int ch = tid; ch < WP * CIN / 8; ch += 256) {
        int iw = ch >> 4;            // 0..63
        int cb = (ch & 15) << 3;     // ci base, 0..120
        bf16x8 v = {0, 0, 0, 0, 0, 0, 0, 0};
        if (iw >= 1 && iw <= WW) {
#pragma unroll
            for (int j = 0; j < 8; ++j)
                v[j] = (short)f2bf(xs[cb + j][iw - 1]);
        }
        outv[ch] = v;
    }
}

// ---------------------------------------------------------------------------
// Main: implicit-GEMM conv.
// R10 = R9 + FULL distance-1 register pipeline (both operands):
//  - Block = 256 threads = 4 waves = 256 Cout x ONE output row;
//    wave = 64 Cout x 64 cols, acc[4][4] (64 AGPR).
//  - A fragments: direct global->reg from L2-hot wpack, dist-1 (afn).
//  - B fragments: ds_read dist-1 (bfn) -> tap t+1's LDS latency hides
//    under tap t's ~310-cyc MFMA cluster. (R9 read B right before use:
//    ~120+ cyc lgkm exposed per tap = the measured 45%-of-ceiling gap.)
//  - B tile [rr(3)][kpos(4)][iw(64)][kin(8)] = 12 KB, double-buffered,
//    staged once per cib. Cib boundary: NO cross-buffer prefetch;
//    vmcnt(0)+lgkmcnt(0)+barrier, then reload bfc from the new buffer
//    (~170 cyc exposed, 3x per block).
//  - Regs: frags 64 VGPR (afc/afn/bfc/bfn) + addr ~= 100 arch + 64 AGPR
//    = 164 unified <= 170 cap at (256,3). R3/R5 lesson: watch FETCH/WRITE
//    for the spill signature.
// ---------------------------------------------------------------------------
__global__ __launch_bounds__(256, 3) void conv_mfma(
    const unsigned short* __restrict__ xp,
    const unsigned short* __restrict__ wpack,
    float* __restrict__ out) {
    // B tile: chunks (rr*4+kpos)*64+iw of 16B; 768 chunks + pad for kw spill
    __shared__ unsigned short Bl[2][3 * 4 * 64 * 8 + 128];

    int tid  = threadIdx.x;
    int lane = tid & 63;
    int wid  = tid >> 6;       // 0..3 = wm (Cout slice of 64)

    // XCD-bijective swizzle: 1792 = 8 * 224; each XCD gets 4 consecutive b's
    int flat = blockIdx.x;
    int swz  = (flat & 7) * 224 + (flat >> 3);
    int b    = swz / 56;       // 0..31
    int oh   = swz % 56;       // output row

    const int klane = lane >> 4;   // k-group (0..3)
    const int fl    = lane & 15;

    f32x4 acc[4][4];
    f32x4 zero = {0.f, 0.f, 0.f, 0.f};
#pragma unroll
    for (int i = 0; i < 4; ++i)
#pragma unroll
        for (int j = 0; j < 4; ++j) acc[i][j] = zero;

    // Per-lane A-fragment base: af(tile,mf) at ap0 + tile*8192 + mf*128 (elems)
    const unsigned short* ap0 = wpack + ((size_t)klane * 256 + wid * 64 + fl) * 8;

    // B staging: thread stages chunks (rr=k, kpos=wid, iw=lane), k=0..2
    const unsigned short* bs =
        xp + (((size_t)(b * HP + oh)) * WP + lane) * CIN + wid * 8;

    // ---- prologue: stage B(cib0); preload afc/bfc for tap (0,0) ----
#pragma unroll
    for (int k = 0; k < 3; ++k)
        gload16(bs + (size_t)k * 8192, &Bl[0][(k * 256 + wid * 64) * 8]);

    bf16x8 afc[4], afn[4], bfc[4], bfn[4];
#pragma unroll
    for (int mf = 0; mf < 4; ++mf)
        afc[mf] = *(const bf16x8*)(ap0 + mf * 128);
    __syncthreads();
#pragma unroll
    for (int nf = 0; nf < 4; ++nf)
        bfc[nf] = *(const bf16x8*)&Bl[0][(klane * 64 + nf * 16 + fl) * 8];

    const unsigned short* apc = ap0;   // += 8192 elems per cib

#pragma unroll 1
    for (int cib = 0; cib < 4; ++cib) {
        const int bbuf = cib & 1;

        // ---- stage B(cib+1) into other buffer: 9 taps of slack ----
        if (cib < 3) {
#pragma unroll
            for (int k = 0; k < 3; ++k)
                gload16(bs + (cib + 1) * 32 + (size_t)k * 8192,
                        &Bl[bbuf ^ 1][(k * 256 + wid * 64) * 8]);
        }

#pragma unroll
        for (int pos = 0; pos < 9; ++pos) {
            // ---- prefetch tap (pos+1) fragments (dist-1, both operands) ----
            if (pos < 8) {
#pragma unroll
                for (int mf = 0; mf < 4; ++mf)
                    afn[mf] = *(const bf16x8*)(apc + (pos + 1) * 32768 + mf * 128);
                const int kh1 = (pos + 1) / 3, kw1 = (pos + 1) - kh1 * 3;
#pragma unroll
                for (int nf = 0; nf < 4; ++nf) {
                    int ch = kh1 * 256 + klane * 64 + nf * 16 + fl + kw1;
                    bfn[nf] = *(const bf16x8*)&Bl[bbuf][ch * 8];
                }
            } else if (cib < 3) {
#pragma unroll
                for (int mf = 0; mf < 4; ++mf)
                    afn[mf] = *(const bf16x8*)(apc + 8192 + mf * 128);
                // bfn for next cib comes from the other buffer: post-barrier only
            }

            // ---- MFMA on afc/bfc (loaded a full tap ago) ----
            __builtin_amdgcn_s_setprio(1);
#pragma unroll
            for (int mf = 0; mf < 4; ++mf)
#pragma unroll
                for (int nf = 0; nf < 4; ++nf)
                    acc[mf][nf] = __builtin_amdgcn_mfma_f32_16x16x32_bf16(
                        afc[mf], bfc[nf], acc[mf][nf], 0, 0, 0);
            __builtin_amdgcn_s_setprio(0);

            // ---- rotate the register pipeline ----
#pragma unroll
            for (int mf = 0; mf < 4; ++mf) afc[mf] = afn[mf];
            if (pos < 8) {
#pragma unroll
                for (int nf = 0; nf < 4; ++nf) bfc[nf] = bfn[nf];
            }
        }

        apc += 8192;
        if (cib < 3) {
            // staging complete (vmcnt) + all waves' reads done (lgkm+barrier)
            asm volatile("s_waitcnt vmcnt(0) lgkmcnt(0)" ::: "memory");
            __builtin_amdgcn_s_barrier();
            // reload bfc for tap (cib+1, pos0) from the freshly staged buffer
#pragma unroll
            for (int nf = 0; nf < 4; ++nf)
                bfc[nf] = *(const bf16x8*)&Bl[bbuf ^ 1][(klane * 64 + nf * 16 + fl) * 8];
        }
    }

    // Epilogue: C/D layout col = lane&15, row = (lane>>4)*4 + reg (m89-verified)
#pragma unroll
    for (int nf = 0; nf < 4; ++nf) {
        int ow = nf * 16 + fl;
        if (ow < WW) {
#pragma unroll
            for (int mf = 0; mf < 4; ++mf) {
                int ob = wid * 64 + mf * 16 + (lane >> 4) * 4;
                float* dst = out + (((size_t)b * COUT + ob) * HH + oh) * WW + ow;
#pragma unroll
                for (int r = 0; r < 4; ++r)
                    dst[(size_t)r * HH * WW] = acc[mf][nf][r];
            }
        }
    }
}

extern "C" void kernel_launch(void* const* d_in, const int* in_sizes, int n_in,
                              void* d_out, int out_size, void* d_ws, size_t ws_size,
                              hipStream_t stream) {
    const float* x    = (const float*)d_in[0];
    const float* dict = (const float*)d_in[1];
    const float* coef = (const float*)d_in[2];
    const int*   idxw = (const int*)d_in[3];
    float* out = (float*)d_out;

    unsigned short* xp    = (unsigned short*)d_ws;
    unsigned short* wpack = xp + XP_ELEMS;

    prep<<<dim3(COUT + HP * NB), dim3(256), 0, stream>>>(x, dict, coef, idxw, wpack, xp);
    conv_mfma<<<dim3(NB * 56), dim3(256), 0, stream>>>(xp, wpack, out);
}